// Round 4
// baseline (156.900 us; speedup 1.0000x reference)
//
#include <hip/hip_runtime.h>
#include <stdint.h>

static constexpr int Kdim  = 1024;    // L
static constexpr int Ncols = 512;     // OUT

typedef __attribute__((ext_vector_type(8))) short bf16x8;
typedef __attribute__((ext_vector_type(4))) float f32x4;

__device__ __forceinline__ unsigned short f2bf(float f) {
  unsigned u = __builtin_bit_cast(unsigned, f);
  u += 0x7FFFu + ((u >> 16) & 1u);          // RNE
  return (unsigned short)(u >> 16);
}
__device__ __forceinline__ unsigned f2bf2(float lo, float hi) {
  unsigned ul = __builtin_bit_cast(unsigned, lo);
  unsigned uh = __builtin_bit_cast(unsigned, hi);
  ul += 0x7FFFu + ((ul >> 16) & 1u);
  uh += 0x7FFFu + ((uh >> 16) & 1u);
  return (ul >> 16) | (uh & 0xFFFF0000u);
}

// async global->LDS, 16B per lane; LDS dest = uniform base + lane*16
__device__ __forceinline__ void gl2lds16(const void* g, void* l) {
  __builtin_amdgcn_global_load_lds(
      (const __attribute__((address_space(1))) void*)g,
      (__attribute__((address_space(3))) void*)l, 16, 0, 0);
}

// ---------------------------------------------------------------------------
// prep_w: 512 blocks: Wt[n][k] = bf16(0.5*(W_in+W_out)+W_root)^T.  ~7 MiB.
// ---------------------------------------------------------------------------
__global__ __launch_bounds__(256) void prep_w(
    const float* __restrict__ Win, const float* __restrict__ Wout,
    const float* __restrict__ Wroot, unsigned short* __restrict__ Wt)
{
  __shared__ unsigned short lds[32 * 36];
  const int t  = threadIdx.x;
  const int b2 = blockIdx.x;
  const int tk0 = (b2 & 31) * 32;
  const int tn0 = (b2 >> 5) * 32;
  {
    const int k  = t >> 3;
    const int nq = (t & 7) * 4;
    const int gi = (tk0 + k) * Ncols + tn0 + nq;
    const float4 wi = *(const float4*)(Win + gi);
    const float4 wo = *(const float4*)(Wout + gi);
    const float4 wr = *(const float4*)(Wroot + gi);
    lds[(nq + 0) * 36 + k] = f2bf(0.5f * (wi.x + wo.x) + wr.x);
    lds[(nq + 1) * 36 + k] = f2bf(0.5f * (wi.y + wo.y) + wr.y);
    lds[(nq + 2) * 36 + k] = f2bf(0.5f * (wi.z + wo.z) + wr.z);
    lds[(nq + 3) * 36 + k] = f2bf(0.5f * (wi.w + wo.w) + wr.w);
  }
  __syncthreads();
  {
    const int n  = t >> 3;
    const int k8 = (t & 7) * 4;
    const ushort4 v = *(const ushort4*)&lds[n * 36 + k8];
    *(ushort4*)(Wt + (size_t)(tn0 + n) * Kdim + tk0 + k8) = v;
  }
}

// ---------------------------------------------------------------------------
// gemm_fused: Y = bf16(x) @ Wt^T + bias.  512 blocks, each owns a 64-row
// m-panel x 256 n-cols (x read from HBM EXACTLY once; the 2 n-sharers of a
// panel sit on the SAME XCD -> second read is an L2 hit; Wt (1 MB) is L2-hot
// everywhere).  256 thr / 4 waves, wave = 32m x 128n (2x8 16x16x32 mfma).
//
// Per k-step (BK=32), double-buffered, ONE barrier:
//   1. STAGE_B(t+1): 4x global_load_lds from Wt -> Bs[nxt]   [vm, L2]
//      sched_barrier(0)  (B must stay oldest in the vm queue)
//   2. frag ds_reads from As/Bs[cur]
//   3. PACKA: regs x(t+1) (loaded last iter) -> bf16 -> ds_write As[nxt]
//   4. LOADX: issue x(t+2) f32 loads (2x float4/lane)        [vm, HBM]
//   5. 16x MFMA
//   6. s_waitcnt vmcnt(2) lgkmcnt(0); s_barrier
//      -> B(t+1) + A-pack landed; x(t+2) stays in flight (~1.5 iter cover).
// Swizzle: 16B slot s of row r holds k-chunk s^((r>>1)&3) (verified layout);
// pack writes slot (c ^ ((r>>1)&3)) so frag reads are unchanged.
// ---------------------------------------------------------------------------
__global__ __launch_bounds__(256, 2) void gemm_fused(
    const float* __restrict__ x, const unsigned short* __restrict__ Wt,
    const float* __restrict__ b_in, const float* __restrict__ b_out,
    const float* __restrict__ b_root, float* __restrict__ Y)
{
  constexpr int ABUF = 64 * 32;              // 2048 shorts (4 KB)
  constexpr int BBUF = 256 * 32;             // 8192 shorts (16 KB)
  __shared__ __attribute__((aligned(16))) short As[2 * ABUF];
  __shared__ __attribute__((aligned(16))) short Bs[2 * BBUF];

  const int bid  = blockIdx.x;
  const int xcd  = bid & 7;
  const int idx  = bid >> 3;
  const int mt   = xcd * 32 + (idx >> 1);    // 64-row panel id [0,256)
  const int half = idx & 1;                  // n-half: 0 or 1
  const int m0   = mt * 64;
  const int n0   = half * 256;

  const int t    = threadIdx.x;
  const int lane = t & 63;
  const int w    = t >> 6;
  const int wm   = w >> 1;                   // 0..1 : 32-row m-slice
  const int wn   = w & 1;                    // 0..1 : 128-col n-slice
  const int quad = lane >> 4;
  const int lm   = lane & 15;

  // --- A staging (reg-pack): wave w covers rows w*16..w*16+15.
  //     lane: row r = w*16 + (lane>>2), f32 chunk c = lane&3 (8 floats);
  //     writes LDS slot s = c ^ ((r>>1)&3)  (== c ^ ((lane>>3)&3)).
  const int arow = w * 16 + (lane >> 2);
  const int ac   = lane & 3;
  const float* gX = x + (size_t)(m0 + arow) * Kdim + ac * 8;
  short* const lA = &As[arow * 32 + (ac ^ ((lane >> 3) & 3)) * 8];

  // --- B staging: wave w covers rows w*64..w*64+63 (4 x 16-row gl2lds).
  const int sr = lane >> 2;
  const int ss = lane & 3;
  const int sc = ss ^ ((sr >> 1) & 3);
  const unsigned short* gB = Wt + (size_t)(n0 + w * 64 + sr) * Kdim + sc * 8;
  short* const lB = &Bs[(w * 64) * 32];
  const int rowK = 16 * Kdim;                // +16 B-rows in global (elems)

  // --- fragment addresses (verified layout)
  const int slot = quad ^ ((lm >> 1) & 3);
  const int aoff = (wm * 32 + lm) * 32 + slot * 8;    // + i*512, i in {0,1}
  const int boff = (wn * 128 + lm) * 32 + slot * 8;   // + j*512, j in 0..7

  f32x4 acc[2][8] = {};
  float4 S0, S1, T0, T1;

#define LOADX(P0, P1, IDX) do {                                           \
    const float* gx_ = gX + (IDX) * 32;                                   \
    P0 = *(const float4*)(gx_);                                           \
    P1 = *(const float4*)(gx_ + 4);                                       \
  } while (0)

#define PACKA(P0, P1, NXT) do {                                           \
    uint4 pk_;                                                            \
    pk_.x = f2bf2(P0.x, P0.y); pk_.y = f2bf2(P0.z, P0.w);                 \
    pk_.z = f2bf2(P1.x, P1.y); pk_.w = f2bf2(P1.z, P1.w);                 \
    *(uint4*)(lA + (NXT) * ABUF) = pk_;                                   \
  } while (0)

#define STAGE_B(TT, BUF) do {                                             \
    gl2lds16(gB + (TT) * 32,            lB + (BUF) * BBUF);               \
    gl2lds16(gB + (TT) * 32 + rowK,     lB + (BUF) * BBUF + 16 * 32);     \
    gl2lds16(gB + (TT) * 32 + 2 * rowK, lB + (BUF) * BBUF + 32 * 32);     \
    gl2lds16(gB + (TT) * 32 + 3 * rowK, lB + (BUF) * BBUF + 48 * 32);     \
  } while (0)

#define SYNC() do {                                                       \
    asm volatile("s_waitcnt vmcnt(2) lgkmcnt(0)" ::: "memory");           \
    __builtin_amdgcn_s_barrier();                                         \
    __builtin_amdgcn_sched_barrier(0);                                    \
  } while (0)

#define KSTEP(TT, PK0, PK1, LD0, LD1) do {                                \
    const int nxt_ = ((TT) + 1) & 1, cur_ = (TT) & 1;                     \
    STAGE_B((TT) + 1, nxt_);                                              \
    __builtin_amdgcn_sched_barrier(0);   /* B stays oldest in vm queue */ \
    bf16x8 af[2], bfr[8];                                                 \
    _Pragma("unroll") for (int i = 0; i < 2; ++i)                         \
      af[i]  = *(const bf16x8*)&As[cur_ * ABUF + aoff + i * 512];         \
    _Pragma("unroll") for (int j = 0; j < 8; ++j)                         \
      bfr[j] = *(const bf16x8*)&Bs[cur_ * BBUF + boff + j * 512];         \
    PACKA(PK0, PK1, nxt_);                                                \
    { int ld_ = (TT) + 2; if (ld_ > 31) ld_ = 31;                         \
      LOADX(LD0, LD1, ld_); }                                             \
    _Pragma("unroll") for (int i = 0; i < 2; ++i)                         \
      _Pragma("unroll") for (int j = 0; j < 8; ++j)                       \
        acc[i][j] = __builtin_amdgcn_mfma_f32_16x16x32_bf16(              \
            af[i], bfr[j], acc[i][j], 0, 0, 0);                           \
    SYNC();                                                               \
  } while (0)

  // prologue: x(0)->S, B(0) staged, x(1)->T, pack x(0) -> As[0]
  LOADX(S0, S1, 0);
  __builtin_amdgcn_sched_barrier(0);
  STAGE_B(0, 0);
  __builtin_amdgcn_sched_barrier(0);
  LOADX(T0, T1, 1);
  PACKA(S0, S1, 0);                          // implicit wait on S
  SYNC();                                    // drains B(0)+pack, keeps T

  #pragma unroll 1
  for (int it = 0; it < 30; it += 2) {
    KSTEP(it,     T0, T1, S0, S1);           // pack x(it+1)=T, load x(it+2)->S
    KSTEP(it + 1, S0, S1, T0, T1);
  }
  KSTEP(30, T0, T1, S0, S1);                 // pack x(31), stage B(31)

  // tail: it = 31, buffers [1], compute only
  {
    bf16x8 af[2], bfr[8];
    #pragma unroll
    for (int i = 0; i < 2; ++i) af[i]  = *(const bf16x8*)&As[ABUF + aoff + i * 512];
    #pragma unroll
    for (int j = 0; j < 8; ++j) bfr[j] = *(const bf16x8*)&Bs[BBUF + boff + j * 512];
    #pragma unroll
    for (int i = 0; i < 2; ++i)
      #pragma unroll
      for (int j = 0; j < 8; ++j)
        acc[i][j] = __builtin_amdgcn_mfma_f32_16x16x32_bf16(af[i], bfr[j], acc[i][j], 0, 0, 0);
  }

#undef KSTEP
#undef SYNC
#undef STAGE_B
#undef PACKA
#undef LOADX

  // epilogue: D[row=(lane>>4)*4+reg][col=lane&15] per 16x16 tile; bias fused
  #pragma unroll
  for (int j = 0; j < 8; ++j) {
    const int gc = n0 + wn * 128 + j * 16 + lm;
    const float bias = 0.5f * (b_in[gc] + b_out[gc]) + b_root[gc];
    #pragma unroll
    for (int i = 0; i < 2; ++i) {
      const int gr = m0 + wm * 32 + i * 16 + quad * 4;
      float* yp = Y + (size_t)gr * Ncols + gc;
      #pragma unroll
      for (int r = 0; r < 4; ++r)
        yp[(size_t)r * Ncols] = acc[i][j][r] + bias;
    }
  }
}

// ---------------------------------------------------------------------------
extern "C" void kernel_launch(void* const* d_in, const int* in_sizes, int n_in,
                              void* d_out, int out_size, void* d_ws, size_t ws_size,
                              hipStream_t stream)
{
  const float* x      = (const float*)d_in[0];
  // d_in[1] = At : dead input (ChebConv K=1 -> no neighbor aggregation)
  const float* W_in   = (const float*)d_in[2];
  const float* b_in   = (const float*)d_in[3];
  const float* W_out  = (const float*)d_in[4];
  const float* b_out  = (const float*)d_in[5];
  const float* W_root = (const float*)d_in[6];
  const float* b_root = (const float*)d_in[7];
  float* y = (float*)d_out;

  unsigned short* Wt = (unsigned short*)d_ws;   // 1 MiB only

  prep_w<<<dim3(512), dim3(256), 0, stream>>>(W_in, W_out, W_root, Wt);
  gemm_fused<<<dim3(512), dim3(256), 0, stream>>>(x, Wt, b_in, b_out, b_root, y);
}